// Round 2
// baseline (333.029 us; speedup 1.0000x reference)
//
#include <hip/hip_runtime.h>
#include <math.h>

// SPP: out = concat(x, mp5(x), mp9(x), mp13(x)), x:(32,512,32,32) fp32.
// mp9 = mp5^2, mp13 = mp5^3 (stride-1, -inf pad => clip-composable).
// One WAVE per (n,c) plane, zero LDS, zero barriers:
//   lane l: row r=l&31, half h=l>>5, holds cols [16h,16h+16) in 16 VGPRs.
//   Row max5: in-lane + 4 partner (l^32) bpermutes for the half boundary.
//   Col max5: +-1 lane bpermutes, two-step (s1 then combine).
// Boundary clipping via source-index clamping (max with self = no-op),
// so there are no -inf constants and no per-value selects.

constexpr int HWSZ = 1024;
constexpr int C_IN = 512;
constexpr int C_OUT = 2048;

__device__ __forceinline__ float bperm(int idx, float v) {
    return __int_as_float(__builtin_amdgcn_ds_bpermute(idx, __float_as_int(v)));
}

__global__ __launch_bounds__(256) void spp_kernel(const float* __restrict__ x,
                                                  float* __restrict__ out) {
    const int lane = threadIdx.x & 63;
    const int wv   = threadIdx.x >> 6;
    const int plane = (blockIdx.x << 2) + wv;    // 0..16383
    const int r = lane & 31;
    const int h = lane >> 5;

    // bpermute byte-indices (pull semantics: receive from lane idx>>2)
    const int idx_part = (lane ^ 32) << 2;
    const int idx_m1   = ((r == 0)  ? lane : (lane - 1)) << 2;  // row r-1 (clamped)
    const int idx_p1   = ((r == 31) ? lane : (lane + 1)) << 2;  // row r+1 (clamped)

    const int n = plane >> 9;
    const int c = plane & 511;

    const size_t inoff = (size_t)plane * HWSZ + (r << 5) + (h << 4);
    const size_t ooff  = (size_t)n * C_OUT * HWSZ + (size_t)c * HWSZ + (r << 5) + (h << 4);

    // ---- load 16 floats (this lane's half-row) and emit identity chunk ----
    const float4* sp = (const float4*)(x + inoff);
    float4 q0 = sp[0], q1 = sp[1], q2 = sp[2], q3 = sp[3];
    float4* op = (float4*)(out + ooff);
    op[0] = q0; op[1] = q1; op[2] = q2; op[3] = q3;

    float v[16];
    v[0]=q0.x; v[1]=q0.y; v[2]=q0.z; v[3]=q0.w;
    v[4]=q1.x; v[5]=q1.y; v[6]=q1.z; v[7]=q1.w;
    v[8]=q2.x; v[9]=q2.y; v[10]=q2.z; v[11]=q2.w;
    v[12]=q3.x; v[13]=q3.y; v[14]=q3.z; v[15]=q3.w;

    #pragma unroll
    for (int p = 1; p <= 3; ++p) {
        // ---------- row pass: rm[i] = max over cols (16h+i-2 .. 16h+i+2) ----------
        // e[i] <-> global col 16h + i - 2; out-of-plane entries substituted
        // with in-window self values (idempotent under max).
        float t14 = bperm(idx_part, v[14]);  // partner col 16h'+14
        float t15 = bperm(idx_part, v[15]);
        float t0  = bperm(idx_part, v[0]);   // partner col 16h'+0
        float t1  = bperm(idx_part, v[1]);

        float e[20];
        e[0]  = h ? t14  : v[0];    // col 14 | clip
        e[1]  = h ? t15  : v[1];    // col 15 | clip
        #pragma unroll
        for (int i = 0; i < 16; ++i) e[2 + i] = v[i];
        e[18] = h ? v[14] : t0;     // clip   | col 16
        e[19] = h ? v[15] : t1;     // clip   | col 17

        float m2[19];
        #pragma unroll
        for (int i = 0; i < 19; ++i) m2[i] = fmaxf(e[i], e[i + 1]);
        float rm[16];
        #pragma unroll
        for (int i = 0; i < 16; ++i)
            rm[i] = fmaxf(fmaxf(m2[i], m2[i + 2]), e[i + 4]);

        // ---------- col pass: v[i] = max over rows (r-2 .. r+2) ----------
        float s1[16];
        #pragma unroll
        for (int i = 0; i < 16; ++i) {
            float up = bperm(idx_m1, rm[i]);   // rm[r-1] (self at r==0)
            float dn = bperm(idx_p1, rm[i]);   // rm[r+1] (self at r==31)
            s1[i] = fmaxf(fmaxf(up, dn), rm[i]);
        }
        #pragma unroll
        for (int i = 0; i < 16; ++i) {
            float u2 = bperm(idx_m1, s1[i]);   // s1[r-1]
            float d2 = bperm(idx_p1, s1[i]);   // s1[r+1]
            v[i] = fmaxf(u2, d2);              // covers rows r-2..r+2
        }

        // ---------- store this pyramid level ----------
        float4 o0 = make_float4(v[0], v[1], v[2], v[3]);
        float4 o1 = make_float4(v[4], v[5], v[6], v[7]);
        float4 o2 = make_float4(v[8], v[9], v[10], v[11]);
        float4 o3 = make_float4(v[12], v[13], v[14], v[15]);
        float4* opp = (float4*)(out + ooff + (size_t)p * C_IN * HWSZ);
        opp[0] = o0; opp[1] = o1; opp[2] = o2; opp[3] = o3;
    }
}

extern "C" void kernel_launch(void* const* d_in, const int* in_sizes, int n_in,
                              void* d_out, int out_size, void* d_ws, size_t ws_size,
                              hipStream_t stream) {
    const float* x = (const float*)d_in[0];
    float* out = (float*)d_out;
    // 16384 planes, 1 wave each, 4 waves (256 threads) per block
    spp_kernel<<<4096, 256, 0, stream>>>(x, out);
}

// Round 3
// 320.271 us; speedup vs baseline: 1.0398x; 1.0398x over previous
//
#include <hip/hip_runtime.h>
#include <math.h>

// SPP: out = concat(x, mp5(x), mp9(x), mp13(x)), x:(32,512,32,32) fp32.
// mp9 = mp5^2, mp13 = mp5^3; mp5 separable, and the two 1-D passes commute.
// One WAVE owns 2 planes + private LDS region -> ZERO barriers, ZERO bpermute.
// Lane l: half h=l>>5 selects plane, sub=l&31 is a row id (row-ownership
// phases) or col id (col-ownership phases). In-lane max5 over 32 registers.
// Pass order alternates so only 3 LDS transposes are needed:
//   stage->LDS, V1(col) -T-> H1(row): store p1 ; H2(row) -T-> V2(col): store
//   p2 ; V3(col) -T-> H3(row): store p3.
// LDS row stride 36 words: col b32 accesses conflict-free ((4r+c)%32),
// row float4 accesses 16B-aligned & bank-uniform. DS ops within a wave are
// in-order -> wave-private LDS needs no __syncthreads.

constexpr int LSTR = 36;
constexpr int PLANE_W = 32 * LSTR;   // 1152 words / plane
constexpr int PAIR_W = 2 * PLANE_W;  // 2304 words / wave
constexpr int HW = 1024;

__device__ __forceinline__ void max5_inplace(float a[32]) {
    float m2[31];
    #pragma unroll
    for (int i = 0; i < 31; ++i) m2[i] = fmaxf(a[i], a[i + 1]);
    const float t2 = a[2];
    a[0] = fmaxf(m2[0], t2);
    a[1] = fmaxf(m2[0], m2[2]);
    #pragma unroll
    for (int i = 2; i < 30; ++i) a[i] = fmaxf(fmaxf(m2[i - 2], m2[i]), a[i + 2]);
    a[30] = fmaxf(m2[28], m2[30]);
    a[31] = fmaxf(m2[29], a[31]);
}

__global__ __launch_bounds__(256, 4) void spp_kernel(const float* __restrict__ x,
                                                     float* __restrict__ out) {
    __shared__ float lds[4 * PAIR_W];   // 36,864 B -> 4 blocks/CU (16 waves)

    const int t = threadIdx.x;
    const int wv = t >> 6;
    const int lane = t & 63;
    const int h = lane >> 5;
    const int sub = lane & 31;

    const int pair = (blockIdx.x << 2) + wv;   // 0..8191 (2 planes each)
    const int P0 = pair << 1;
    const int n = P0 >> 9;
    const int c0 = P0 & 511;

    const float* src = x + (size_t)pair * 2048;
    float* ob0 = out + ((size_t)n * 2048 + c0) * HW;          // identity chunk
    const size_t levbase = ((size_t)n * 2048 + (c0 + h)) * HW; // + p*512*HW

    float* L = lds + wv * PAIR_W;       // wave-private scratch
    float* Lp = L + h * PLANE_W;        // this lane's plane

    // ---- coalesced load, identity store, stage to LDS ----
    float4 q[8];
    #pragma unroll
    for (int k = 0; k < 8; ++k) q[k] = *(const float4*)(src + k * 256 + lane * 4);
    #pragma unroll
    for (int k = 0; k < 8; ++k) *(float4*)(ob0 + k * 256 + lane * 4) = q[k];
    #pragma unroll
    for (int k = 0; k < 8; ++k) {
        const int e = k * 256 + lane * 4;
        const int w = ((e >> 10) * PLANE_W) + (((e >> 5) & 31) * LSTR) + (e & 31);
        *(float4*)(L + w) = q[k];
    }

    float a[32];

    // ---- V1: column ownership (plane h, col sub) ----
    #pragma unroll
    for (int r = 0; r < 32; ++r) a[r] = Lp[r * LSTR + sub];
    max5_inplace(a);
    // transpose col->row
    #pragma unroll
    for (int r = 0; r < 32; ++r) Lp[r * LSTR + sub] = a[r];
    #pragma unroll
    for (int k = 0; k < 8; ++k)
        *(float4*)(&a[k * 4]) = *(const float4*)(Lp + sub * LSTR + k * 4);
    // ---- H1 -> p1 (row ownership), store ----
    max5_inplace(a);
    {
        float* o = out + levbase + (size_t)512 * HW + sub * 32;
        #pragma unroll
        for (int k = 0; k < 8; ++k) *(float4*)(o + k * 4) = *(const float4*)(&a[k * 4]);
    }

    // ---- H2 (row ownership) ----
    max5_inplace(a);
    // transpose row->col
    #pragma unroll
    for (int k = 0; k < 8; ++k)
        *(float4*)(Lp + sub * LSTR + k * 4) = *(const float4*)(&a[k * 4]);
    #pragma unroll
    for (int r = 0; r < 32; ++r) a[r] = Lp[r * LSTR + sub];
    // ---- V2 -> p2 (col ownership), store coalesced ----
    max5_inplace(a);
    {
        float* o = out + levbase + (size_t)1024 * HW + sub;
        #pragma unroll
        for (int r = 0; r < 32; ++r) o[r * 32] = a[r];
    }

    // ---- V3 (col ownership) ----
    max5_inplace(a);
    // transpose col->row
    #pragma unroll
    for (int r = 0; r < 32; ++r) Lp[r * LSTR + sub] = a[r];
    #pragma unroll
    for (int k = 0; k < 8; ++k)
        *(float4*)(&a[k * 4]) = *(const float4*)(Lp + sub * LSTR + k * 4);
    // ---- H3 -> p3 (row ownership), store ----
    max5_inplace(a);
    {
        float* o = out + levbase + (size_t)1536 * HW + sub * 32;
        #pragma unroll
        for (int k = 0; k < 8; ++k) *(float4*)(o + k * 4) = *(const float4*)(&a[k * 4]);
    }
}

extern "C" void kernel_launch(void* const* d_in, const int* in_sizes, int n_in,
                              void* d_out, int out_size, void* d_ws, size_t ws_size,
                              hipStream_t stream) {
    const float* x = (const float*)d_in[0];
    float* out = (float*)d_out;
    // 16384 planes / 2 planes-per-wave / 4 waves-per-block = 2048 blocks
    spp_kernel<<<2048, 256, 0, stream>>>(x, out);
}